// Round 1
// baseline (2351.025 us; speedup 1.0000x reference)
//
#include <hip/hip_runtime.h>

#define N_NODES 100000
#define N_EDGES 1200000

// ---------------- fill ----------------
__global__ void fill_kernel(float* __restrict__ p, float v, int n) {
    int i = blockIdx.x * blockDim.x + threadIdx.x;
    int stride = gridDim.x * blockDim.x;
    for (; i < n; i += stride) p[i] = v;
}

// ---------------- degree: deg[dst[e]] += 1 (deg pre-filled with 1.0 for self-loop)
__global__ void degree_kernel(const int* __restrict__ dst, float* __restrict__ deg, int E) {
    int e = blockIdx.x * blockDim.x + threadIdx.x;
    if (e < E) atomicAdd(&deg[dst[e]], 1.0f);
}

__global__ void rsqrt_kernel(float* __restrict__ d, int n) {
    int i = blockIdx.x * blockDim.x + threadIdx.x;
    if (i < n) d[i] = rsqrtf(d[i]);
}

// ---------------- skinny GEMM: H[n,DOUT] = X[n,DIN] @ W[DIN,DOUT] (+bias) ----------------
template<int DIN, int DOUT>
__global__ void gemm_kernel(const float* __restrict__ X, const float* __restrict__ W,
                            const float* __restrict__ bias,
                            float* __restrict__ H, int n) {
    constexpr int ROWS = 256 / DOUT;
    __shared__ float sW[DIN * DOUT];
    __shared__ float sX[ROWS * DIN];
    for (int i = threadIdx.x; i < DIN * DOUT; i += 256) sW[i] = W[i];
    size_t base = (size_t)blockIdx.x * ROWS * DIN;
    for (int i = threadIdx.x; i < ROWS * DIN; i += 256) {
        size_t g = base + i;
        sX[i] = (g < (size_t)n * DIN) ? X[g] : 0.0f;
    }
    __syncthreads();
    int lr = threadIdx.x / DOUT;      // local row
    int c  = threadIdx.x % DOUT;      // output col
    int r  = blockIdx.x * ROWS + lr;
    if (r >= n) return;
    float acc = 0.0f;
#pragma unroll
    for (int k = 0; k < DIN; ++k)
        acc = fmaf(sX[lr * DIN + k], sW[k * DOUT + c], acc);
    if (bias) acc += bias[c];
    H[(size_t)r * DOUT + c] = acc;
}

// ---------------- edge scatter: agg[dst] += dinv[src]*dinv[dst] * tmp[src] ----------------
// 16 threads per edge, float4 gather, 4 scalar fp32 atomics per thread.
__global__ void scatter_kernel(const int* __restrict__ src, const int* __restrict__ dst,
                               const float* __restrict__ dinv, const float* __restrict__ tmp,
                               float* __restrict__ agg, int E) {
    int t = blockIdx.x * 256 + threadIdx.x;
    int e = t >> 4;
    int q = t & 15;
    if (e >= E) return;
    int s = src[e], d = dst[e];
    float norm = dinv[s] * dinv[d];
    float4 v = ((const float4*)(tmp + (size_t)s * 64))[q];
    float* a = agg + (size_t)d * 64 + q * 4;
    atomicAdd(a + 0, v.x * norm);
    atomicAdd(a + 1, v.y * norm);
    atomicAdd(a + 2, v.z * norm);
    atomicAdd(a + 3, v.w * norm);
}

// ---------------- epilogue: h = relu(agg + dinv^2 * tmp + b) ----------------
__global__ void epilogue_kernel(const float* __restrict__ agg, const float* __restrict__ tmp,
                                const float* __restrict__ dinv, const float* __restrict__ b,
                                float* __restrict__ h, int total /* = N*64 */) {
    int i = blockIdx.x * 256 + threadIdx.x;
    if (i >= total) return;
    int node = i >> 6, d = i & 63;
    float di = dinv[node];
    float v = fmaf(di * di, tmp[i], agg[i]) + b[d];
    h[i] = fmaxf(v, 0.0f);
}

extern "C" void kernel_launch(void* const* d_in, const int* in_sizes, int n_in,
                              void* d_out, int out_size, void* d_ws, size_t ws_size,
                              hipStream_t stream) {
    const float* x  = (const float*)d_in[0];
    const int*   ei = (const int*)d_in[1];   // [2*E]: src row, then dst row
    const float* W1 = (const float*)d_in[2];
    const float* b1 = (const float*)d_in[3];
    const float* W2 = (const float*)d_in[4];
    const float* b2 = (const float*)d_in[5];
    const float* Wl = (const float*)d_in[6];
    const float* bl = (const float*)d_in[7];
    float* out = (float*)d_out;

    const int N = N_NODES;
    const int E = N_EDGES;
    const int* src = ei;
    const int* dst = ei + E;

    // workspace layout (fp32): dinv[N] | tmp[N*64] | agg[N*64] | h[N*64]
    char* ws = (char*)d_ws;
    size_t off = 0;
    float* dinv = (float*)(ws + off); off += ((size_t)N * 4 + 511) & ~(size_t)511;
    float* tmp  = (float*)(ws + off); off += (size_t)N * 64 * 4;
    float* agg  = (float*)(ws + off); off += (size_t)N * 64 * 4;
    float* h    = (float*)(ws + off); off += (size_t)N * 64 * 4;
    (void)ws_size;

    const int TOTAL = N * 64;

    // ---- degrees / norms ----
    fill_kernel<<<512, 256, 0, stream>>>(dinv, 1.0f, N);
    degree_kernel<<<(E + 255) / 256, 256, 0, stream>>>(dst, dinv, E);
    rsqrt_kernel<<<(N + 255) / 256, 256, 0, stream>>>(dinv, N);

    // ---- layer 1 ----
    gemm_kernel<64, 64><<<(N + 3) / 4, 256, 0, stream>>>(x, W1, nullptr, tmp, N);
    fill_kernel<<<4096, 256, 0, stream>>>(agg, 0.0f, TOTAL);
    scatter_kernel<<<(E * 16 + 255) / 256, 256, 0, stream>>>(src, dst, dinv, tmp, agg, E);
    epilogue_kernel<<<(TOTAL + 255) / 256, 256, 0, stream>>>(agg, tmp, dinv, b1, h, TOTAL);

    // ---- layer 2 ----
    gemm_kernel<64, 64><<<(N + 3) / 4, 256, 0, stream>>>(h, W2, nullptr, tmp, N);
    fill_kernel<<<4096, 256, 0, stream>>>(agg, 0.0f, TOTAL);
    scatter_kernel<<<(E * 16 + 255) / 256, 256, 0, stream>>>(src, dst, dinv, tmp, agg, E);
    epilogue_kernel<<<(TOTAL + 255) / 256, 256, 0, stream>>>(agg, tmp, dinv, b2, h, TOTAL);

    // ---- head: out = h @ Wl + bl ----
    gemm_kernel<64, 32><<<(N + 7) / 8, 256, 0, stream>>>(h, Wl, bl, out, N);
}

// Round 2
// 452.691 us; speedup vs baseline: 5.1934x; 5.1934x over previous
//
#include <hip/hip_runtime.h>

#define N_NODES 100000
#define N_EDGES 1200000

#define SCAN_BLOCK 256
#define SCAN_ITEMS 4
#define SCAN_CHUNK (SCAN_BLOCK * SCAN_ITEMS)   // 1024
#define NB_SCAN ((N_NODES + SCAN_CHUNK - 1) / SCAN_CHUNK)  // 98

// ---------------- zero int ----------------
__global__ void zero_int_kernel(int* __restrict__ p, int n) {
    int i = blockIdx.x * blockDim.x + threadIdx.x;
    int stride = gridDim.x * blockDim.x;
    for (; i < n; i += stride) p[i] = 0;
}

// ---------------- histogram: counts[dst[e]]++ ----------------
__global__ void hist_kernel(const int* __restrict__ dst, int* __restrict__ counts, int E) {
    int e = blockIdx.x * blockDim.x + threadIdx.x;
    if (e < E) atomicAdd(&counts[dst[e]], 1);
}

// ---------------- dinv = rsqrt(counts + 1) ----------------
__global__ void dinv_kernel(const int* __restrict__ counts, float* __restrict__ dinv, int n) {
    int i = blockIdx.x * blockDim.x + threadIdx.x;
    if (i < n) dinv[i] = rsqrtf((float)(counts[i] + 1));
}

// ---------------- exclusive scan of counts -> row_start (3 kernels) ----------------
__global__ void scan1_kernel(const int* __restrict__ counts, int* __restrict__ out,
                             int* __restrict__ blk_sums, int n) {
    __shared__ int sdata[SCAN_BLOCK];
    int base = blockIdx.x * SCAN_CHUNK + threadIdx.x * SCAN_ITEMS;
    int v[SCAN_ITEMS];
    int tsum = 0;
#pragma unroll
    for (int i = 0; i < SCAN_ITEMS; ++i) {
        int idx = base + i;
        v[i] = (idx < n) ? counts[idx] : 0;
        tsum += v[i];
    }
    sdata[threadIdx.x] = tsum;
    __syncthreads();
    for (int offset = 1; offset < SCAN_BLOCK; offset <<= 1) {
        int t = (threadIdx.x >= offset) ? sdata[threadIdx.x - offset] : 0;
        __syncthreads();
        sdata[threadIdx.x] += t;
        __syncthreads();
    }
    int excl = sdata[threadIdx.x] - tsum;
    if (threadIdx.x == SCAN_BLOCK - 1) blk_sums[blockIdx.x] = sdata[threadIdx.x];
    int run = excl;
#pragma unroll
    for (int i = 0; i < SCAN_ITEMS; ++i) {
        int idx = base + i;
        if (idx < n) out[idx] = run;
        run += v[i];
    }
}

__global__ void scan2_kernel(int* __restrict__ blk_sums, int nb) {
    __shared__ int sdata[SCAN_BLOCK];
    int v = (threadIdx.x < nb) ? blk_sums[threadIdx.x] : 0;
    sdata[threadIdx.x] = v;
    __syncthreads();
    for (int offset = 1; offset < SCAN_BLOCK; offset <<= 1) {
        int t = (threadIdx.x >= offset) ? sdata[threadIdx.x - offset] : 0;
        __syncthreads();
        sdata[threadIdx.x] += t;
        __syncthreads();
    }
    if (threadIdx.x < nb) blk_sums[threadIdx.x] = sdata[threadIdx.x] - v;  // exclusive
}

__global__ void scan3_kernel(int* __restrict__ row_start, int* __restrict__ cursor,
                             const int* __restrict__ blk_sums, int n) {
    int i = blockIdx.x * blockDim.x + threadIdx.x;
    if (i < n) {
        int v = row_start[i] + blk_sums[i / SCAN_CHUNK];
        row_start[i] = v;
        cursor[i] = v;
    }
}

// ---------------- bucket fill: sort src ids by dst ----------------
__global__ void bucket_kernel(const int* __restrict__ src, const int* __restrict__ dst,
                              int* __restrict__ cursor, int* __restrict__ srcs_sorted, int E) {
    int e = blockIdx.x * blockDim.x + threadIdx.x;
    if (e < E) {
        int pos = atomicAdd(&cursor[dst[e]], 1);
        srcs_sorted[pos] = src[e];
    }
}

// ---------------- skinny GEMM: H[n,DOUT] = rowscale[r] * (X[n,DIN] @ W) (+bias) ----------------
template<int DIN, int DOUT>
__global__ void gemm_kernel(const float* __restrict__ X, const float* __restrict__ W,
                            const float* __restrict__ bias, const float* __restrict__ rowscale,
                            float* __restrict__ H, int n) {
    constexpr int ROWS = 256 / DOUT;
    __shared__ float sW[DIN * DOUT];
    __shared__ float sX[ROWS * DIN];
    for (int i = threadIdx.x; i < DIN * DOUT; i += 256) sW[i] = W[i];
    size_t base = (size_t)blockIdx.x * ROWS * DIN;
    for (int i = threadIdx.x; i < ROWS * DIN; i += 256) {
        size_t g = base + i;
        sX[i] = (g < (size_t)n * DIN) ? X[g] : 0.0f;
    }
    __syncthreads();
    int lr = threadIdx.x / DOUT;
    int c  = threadIdx.x % DOUT;
    int r  = blockIdx.x * ROWS + lr;
    if (r >= n) return;
    float acc = 0.0f;
#pragma unroll
    for (int k = 0; k < DIN; ++k)
        acc = fmaf(sX[lr * DIN + k], sW[k * DOUT + c], acc);
    if (rowscale) acc *= rowscale[r];
    if (bias) acc += bias[c];
    H[(size_t)r * DOUT + c] = acc;
}

// ---------------- gather aggregation + epilogue ----------------
// tmp rows are pre-scaled by dinv[row]. For node v:
//   h[v] = relu(dinv[v] * (tmp[v] + sum_{e: dst=v} tmp[src_e]) + b)
// 16 threads per node, float4 per thread.
__global__ void aggregate_kernel(const float* __restrict__ tmp,
                                 const int* __restrict__ row_start,
                                 const int* __restrict__ counts,
                                 const int* __restrict__ srcs_sorted,
                                 const float* __restrict__ dinv,
                                 const float* __restrict__ b,
                                 float* __restrict__ h, int n) {
    int t = blockIdx.x * 256 + threadIdx.x;
    int v = t >> 4;
    int q = t & 15;
    if (v >= n) return;
    int beg = row_start[v];
    int end = beg + counts[v];
    float4 acc = ((const float4*)(tmp + (size_t)v * 64))[q];  // self-loop term
    float4 acc2 = make_float4(0.f, 0.f, 0.f, 0.f);
    int e = beg;
    for (; e + 1 < end; e += 2) {
        int s0 = srcs_sorted[e];
        int s1 = srcs_sorted[e + 1];
        float4 m0 = ((const float4*)(tmp + (size_t)s0 * 64))[q];
        float4 m1 = ((const float4*)(tmp + (size_t)s1 * 64))[q];
        acc.x += m0.x; acc.y += m0.y; acc.z += m0.z; acc.w += m0.w;
        acc2.x += m1.x; acc2.y += m1.y; acc2.z += m1.z; acc2.w += m1.w;
    }
    if (e < end) {
        int s0 = srcs_sorted[e];
        float4 m0 = ((const float4*)(tmp + (size_t)s0 * 64))[q];
        acc.x += m0.x; acc.y += m0.y; acc.z += m0.z; acc.w += m0.w;
    }
    acc.x += acc2.x; acc.y += acc2.y; acc.z += acc2.z; acc.w += acc2.w;
    float dv = dinv[v];
    float4 bb = ((const float4*)b)[q];
    float4 r;
    r.x = fmaxf(fmaf(dv, acc.x, bb.x), 0.0f);
    r.y = fmaxf(fmaf(dv, acc.y, bb.y), 0.0f);
    r.z = fmaxf(fmaf(dv, acc.z, bb.z), 0.0f);
    r.w = fmaxf(fmaf(dv, acc.w, bb.w), 0.0f);
    ((float4*)(h + (size_t)v * 64))[q] = r;
}

extern "C" void kernel_launch(void* const* d_in, const int* in_sizes, int n_in,
                              void* d_out, int out_size, void* d_ws, size_t ws_size,
                              hipStream_t stream) {
    const float* x  = (const float*)d_in[0];
    const int*   ei = (const int*)d_in[1];   // [2*E]: src row, then dst row
    const float* W1 = (const float*)d_in[2];
    const float* b1 = (const float*)d_in[3];
    const float* W2 = (const float*)d_in[4];
    const float* b2 = (const float*)d_in[5];
    const float* Wl = (const float*)d_in[6];
    const float* bl = (const float*)d_in[7];
    float* out = (float*)d_out;

    const int N = N_NODES;
    const int E = N_EDGES;
    const int* src = ei;
    const int* dst = ei + E;

    // workspace layout:
    // dinv[N] f32 | counts[N] i32 | row_start[N] i32 | cursor[N] i32 | blk_sums[128] i32
    // | srcs_sorted[E] i32 | tmp[N*64] f32 | h[N*64] f32
    char* ws = (char*)d_ws;
    size_t off = 0;
    auto align = [](size_t v) { return (v + 511) & ~(size_t)511; };
    float* dinv      = (float*)(ws + off); off = align(off + (size_t)N * 4);
    int* counts      = (int*)(ws + off);   off = align(off + (size_t)N * 4);
    int* row_start   = (int*)(ws + off);   off = align(off + (size_t)N * 4);
    int* cursor      = (int*)(ws + off);   off = align(off + (size_t)N * 4);
    int* blk_sums    = (int*)(ws + off);   off = align(off + 128 * 4);
    int* srcs_sorted = (int*)(ws + off);   off = align(off + (size_t)E * 4);
    float* tmp       = (float*)(ws + off); off = align(off + (size_t)N * 64 * 4);
    float* h         = (float*)(ws + off); off = align(off + (size_t)N * 64 * 4);
    (void)ws_size;

    // ---- CSR build ----
    zero_int_kernel<<<512, 256, 0, stream>>>(counts, N);
    hist_kernel<<<(E + 255) / 256, 256, 0, stream>>>(dst, counts, E);
    dinv_kernel<<<(N + 255) / 256, 256, 0, stream>>>(counts, dinv, N);
    scan1_kernel<<<NB_SCAN, SCAN_BLOCK, 0, stream>>>(counts, row_start, blk_sums, N);
    scan2_kernel<<<1, SCAN_BLOCK, 0, stream>>>(blk_sums, NB_SCAN);
    scan3_kernel<<<(N + 255) / 256, 256, 0, stream>>>(row_start, cursor, blk_sums, N);
    bucket_kernel<<<(E + 255) / 256, 256, 0, stream>>>(src, dst, cursor, srcs_sorted, E);

    // ---- layer 1: tmp = dinv * (x @ W1); h = relu(dinv * gather(tmp) + b1) ----
    gemm_kernel<64, 64><<<(N + 3) / 4, 256, 0, stream>>>(x, W1, nullptr, dinv, tmp, N);
    aggregate_kernel<<<(N * 16 + 255) / 256, 256, 0, stream>>>(
        tmp, row_start, counts, srcs_sorted, dinv, b1, h, N);

    // ---- layer 2 ----
    gemm_kernel<64, 64><<<(N + 3) / 4, 256, 0, stream>>>(h, W2, nullptr, dinv, tmp, N);
    aggregate_kernel<<<(N * 16 + 255) / 256, 256, 0, stream>>>(
        tmp, row_start, counts, srcs_sorted, dinv, b2, h, N);

    // ---- head: out = h @ Wl + bl ----
    gemm_kernel<64, 32><<<(N + 7) / 8, 256, 0, stream>>>(h, Wl, bl, nullptr, out, N);
}

// Round 3
// 337.701 us; speedup vs baseline: 6.9619x; 1.3405x over previous
//
#include <hip/hip_runtime.h>

#define N_NODES 100000
#define N_EDGES 1200000

#define BIN_SHIFT 6
#define NODES_PER_BIN 64                       // 1 << BIN_SHIFT
#define NBINS ((N_NODES + NODES_PER_BIN - 1) >> BIN_SHIFT)   // 1563
#define CAP 1024                               // max edges per bucket (mean 768, sigma ~28)
#define EPB 8192                               // edges per binning block
#define NBLK_BIN ((N_EDGES + EPB - 1) / EPB)   // 147

// ---------------- zero int ----------------
__global__ void zero_int_kernel(int* __restrict__ p, int n) {
    int i = blockIdx.x * blockDim.x + threadIdx.x;
    if (i < n) p[i] = 0;
}

// ---------------- binning: edges -> fixed-stride bucket regions ----------------
// packed word: src (bits 0..16) | (dst & 63) << 17
__global__ void binning_kernel(const int* __restrict__ src, const int* __restrict__ dst,
                               int* __restrict__ gcursor, unsigned int* __restrict__ binned,
                               int E) {
    __shared__ unsigned int stage[EPB];      // 32 KB
    __shared__ unsigned short sbin[EPB];     // 16 KB
    __shared__ unsigned int hist[NBINS];     // ~6.3 KB
    int t = threadIdx.x;
    int e_base = blockIdx.x * EPB;

    for (int b = t; b < NBINS; b += 256) hist[b] = 0;
    __syncthreads();

    // Phase A: stage + histogram
#pragma unroll
    for (int j = 0; j < EPB / 256; ++j) {
        int idx = e_base + t + j * 256;
        if (idx < E) {
            int s = src[idx];
            int d = dst[idx];
            unsigned int bin = (unsigned int)d >> BIN_SHIFT;
            unsigned int p = (unsigned int)s | (((unsigned int)d & 63u) << 17);
            stage[t + j * 256] = p;
            sbin[t + j * 256] = (unsigned short)bin;
            atomicAdd(&hist[bin], 1u);
        }
    }
    __syncthreads();

    // Phase B: claim global runs; hist[b] becomes the running global position
    for (int b = t; b < NBINS; b += 256) {
        unsigned int c = hist[b];
        if (c) hist[b] = (unsigned int)(b * CAP) + (unsigned int)atomicAdd(&gcursor[b], (int)c);
    }
    __syncthreads();

    // Phase C: scatter packed words into contiguous runs
#pragma unroll
    for (int j = 0; j < EPB / 256; ++j) {
        int idx = e_base + t + j * 256;
        if (idx < E) {
            unsigned int bin = sbin[t + j * 256];
            unsigned int pos = atomicAdd(&hist[bin], 1u);
            binned[pos] = stage[t + j * 256];
        }
    }
}

// ---------------- dinv: per-bucket local degree count -> rsqrt(deg+1) ----------------
__global__ void dinv_kernel(const unsigned int* __restrict__ binned,
                            const int* __restrict__ gcursor,
                            float* __restrict__ dinv) {
    __shared__ unsigned int counts[NODES_PER_BIN];
    int bin = blockIdx.x;
    int t = threadIdx.x;
    if (t < NODES_PER_BIN) counts[t] = 0;
    __syncthreads();
    int nb = gcursor[bin];
    const unsigned int* eb = binned + (size_t)bin * CAP;
    for (int i = t; i < nb; i += 256) atomicAdd(&counts[eb[i] >> 17], 1u);
    __syncthreads();
    if (t < NODES_PER_BIN) {
        int node = bin * NODES_PER_BIN + t;
        if (node < N_NODES) dinv[node] = rsqrtf((float)(counts[t] + 1u));
    }
}

// ---------------- skinny GEMM: H[n,DOUT] = rowscale[r] * (X[n,DIN] @ W) (+bias) ----------------
template<int DIN, int DOUT>
__global__ void gemm_kernel(const float* __restrict__ X, const float* __restrict__ W,
                            const float* __restrict__ bias, const float* __restrict__ rowscale,
                            float* __restrict__ H, int n) {
    constexpr int ROWS = 256 / DOUT;
    __shared__ float sW[DIN * DOUT];
    __shared__ float sX[ROWS * DIN];
    for (int i = threadIdx.x; i < DIN * DOUT; i += 256) sW[i] = W[i];
    size_t base = (size_t)blockIdx.x * ROWS * DIN;
    for (int i = threadIdx.x; i < ROWS * DIN; i += 256) {
        size_t g = base + i;
        sX[i] = (g < (size_t)n * DIN) ? X[g] : 0.0f;
    }
    __syncthreads();
    int lr = threadIdx.x / DOUT;
    int c  = threadIdx.x % DOUT;
    int r  = blockIdx.x * ROWS + lr;
    if (r >= n) return;
    float acc = 0.0f;
#pragma unroll
    for (int k = 0; k < DIN; ++k)
        acc = fmaf(sX[lr * DIN + k], sW[k * DOUT + c], acc);
    if (rowscale) acc *= rowscale[r];
    if (bias) acc += bias[c];
    H[(size_t)r * DOUT + c] = acc;
}

// ---------------- fused local-CSR + gather aggregation + epilogue ----------------
// tmp rows are pre-scaled by dinv[row]. For node v:
//   h[v] = relu(dinv[v] * (tmp[v] + sum_{e: dst=v} tmp[src_e]) + b)
__global__ void aggregate_kernel(const float* __restrict__ tmp,
                                 const unsigned int* __restrict__ binned,
                                 const int* __restrict__ gcursor,
                                 const float* __restrict__ dinv,
                                 const float* __restrict__ b,
                                 float* __restrict__ h) {
    __shared__ unsigned int eLDS[CAP];             // 4 KB
    __shared__ unsigned int srcs[CAP];             // 4 KB
    __shared__ unsigned int counts[NODES_PER_BIN];
    __shared__ unsigned int scan[NODES_PER_BIN];
    __shared__ unsigned int offs[NODES_PER_BIN];
    __shared__ unsigned int cur[NODES_PER_BIN];
    int bin = blockIdx.x;
    int t = threadIdx.x;
    int nb = gcursor[bin];
    const unsigned int* eb = binned + (size_t)bin * CAP;

    if (t < NODES_PER_BIN) counts[t] = 0;
    __syncthreads();
    // load + count
    for (int i = t; i < nb; i += 256) {
        unsigned int p = eb[i];
        eLDS[i] = p;
        atomicAdd(&counts[p >> 17], 1u);
    }
    __syncthreads();
    // exclusive scan of counts (Hillis-Steele, all threads hit barriers)
    if (t < NODES_PER_BIN) scan[t] = counts[t];
    __syncthreads();
    for (int step = 1; step < NODES_PER_BIN; step <<= 1) {
        unsigned int v = 0;
        if (t < NODES_PER_BIN && t >= step) v = scan[t - step];
        __syncthreads();
        if (t < NODES_PER_BIN) scan[t] += v;
        __syncthreads();
    }
    if (t < NODES_PER_BIN) {
        offs[t] = scan[t] - counts[t];
        cur[t] = 0;
    }
    __syncthreads();
    // place srcs into local CSR order
    for (int i = t; i < nb; i += 256) {
        unsigned int p = eLDS[i];
        unsigned int l = p >> 17;
        unsigned int pos = offs[l] + atomicAdd(&cur[l], 1u);
        srcs[pos] = p & 0x1FFFFu;
    }
    __syncthreads();
    // gather: 16 threads per node, 16 nodes per pass, 4 passes
    int q = t & 15;             // feature quad
    int lnode0 = t >> 4;        // 0..15
    const float4* tmp4 = (const float4*)tmp;
    float4 bb = ((const float4*)b)[q];
#pragma unroll
    for (int g = 0; g < 4; ++g) {
        int ln = g * 16 + lnode0;
        int node = bin * NODES_PER_BIN + ln;
        if (node < N_NODES) {
            int deg = (int)counts[ln];
            int beg = (int)offs[ln];
            float4 acc = tmp4[(size_t)node * 16 + q];     // self-loop term
            float4 acc2 = make_float4(0.f, 0.f, 0.f, 0.f);
            int e = 0;
            for (; e + 1 < deg; e += 2) {
                unsigned int s0 = srcs[beg + e];
                unsigned int s1 = srcs[beg + e + 1];
                float4 m0 = tmp4[(size_t)s0 * 16 + q];
                float4 m1 = tmp4[(size_t)s1 * 16 + q];
                acc.x += m0.x; acc.y += m0.y; acc.z += m0.z; acc.w += m0.w;
                acc2.x += m1.x; acc2.y += m1.y; acc2.z += m1.z; acc2.w += m1.w;
            }
            if (e < deg) {
                unsigned int s0 = srcs[beg + e];
                float4 m0 = tmp4[(size_t)s0 * 16 + q];
                acc.x += m0.x; acc.y += m0.y; acc.z += m0.z; acc.w += m0.w;
            }
            acc.x += acc2.x; acc.y += acc2.y; acc.z += acc2.z; acc.w += acc2.w;
            float dv = dinv[node];
            float4 r;
            r.x = fmaxf(fmaf(dv, acc.x, bb.x), 0.0f);
            r.y = fmaxf(fmaf(dv, acc.y, bb.y), 0.0f);
            r.z = fmaxf(fmaf(dv, acc.z, bb.z), 0.0f);
            r.w = fmaxf(fmaf(dv, acc.w, bb.w), 0.0f);
            ((float4*)(h + (size_t)node * 64))[q] = r;
        }
    }
}

extern "C" void kernel_launch(void* const* d_in, const int* in_sizes, int n_in,
                              void* d_out, int out_size, void* d_ws, size_t ws_size,
                              hipStream_t stream) {
    const float* x  = (const float*)d_in[0];
    const int*   ei = (const int*)d_in[1];   // [2*E]: src row, then dst row
    const float* W1 = (const float*)d_in[2];
    const float* b1 = (const float*)d_in[3];
    const float* W2 = (const float*)d_in[4];
    const float* b2 = (const float*)d_in[5];
    const float* Wl = (const float*)d_in[6];
    const float* bl = (const float*)d_in[7];
    float* out = (float*)d_out;

    const int N = N_NODES;
    const int E = N_EDGES;
    const int* src = ei;
    const int* dst = ei + E;

    // workspace: gcursor[NBINS] i32 | dinv[N] f32 | binned[NBINS*CAP] u32 | tmp[N*64] f32 | h[N*64] f32
    char* ws = (char*)d_ws;
    size_t off = 0;
    auto align = [](size_t v) { return (v + 511) & ~(size_t)511; };
    int* gcursor         = (int*)(ws + off);          off = align(off + (size_t)NBINS * 4);
    float* dinv          = (float*)(ws + off);        off = align(off + (size_t)N * 4);
    unsigned int* binned = (unsigned int*)(ws + off); off = align(off + (size_t)NBINS * CAP * 4);
    float* tmp           = (float*)(ws + off);        off = align(off + (size_t)N * 64 * 4);
    float* h             = (float*)(ws + off);        off = align(off + (size_t)N * 64 * 4);
    (void)ws_size;

    // ---- binned COO build ----
    zero_int_kernel<<<(NBINS + 255) / 256, 256, 0, stream>>>(gcursor, NBINS);
    binning_kernel<<<NBLK_BIN, 256, 0, stream>>>(src, dst, gcursor, binned, E);
    dinv_kernel<<<NBINS, 256, 0, stream>>>(binned, gcursor, dinv);

    // ---- layer 1: tmp = dinv * (x @ W1); h = relu(dinv * gather(tmp) + b1) ----
    gemm_kernel<64, 64><<<(N + 3) / 4, 256, 0, stream>>>(x, W1, nullptr, dinv, tmp, N);
    aggregate_kernel<<<NBINS, 256, 0, stream>>>(tmp, binned, gcursor, dinv, b1, h);

    // ---- layer 2 ----
    gemm_kernel<64, 64><<<(N + 3) / 4, 256, 0, stream>>>(h, W2, nullptr, dinv, tmp, N);
    aggregate_kernel<<<NBINS, 256, 0, stream>>>(tmp, binned, gcursor, dinv, b2, h);

    // ---- head: out = h @ Wl + bl ----
    gemm_kernel<64, 32><<<(N + 7) / 8, 256, 0, stream>>>(h, Wl, bl, nullptr, out, N);
}